// Round 2
// baseline (940.937 us; speedup 1.0000x reference)
//
#include <hip/hip_runtime.h>

#define NB   32      // batch
#define DIM  4096
#define HQ   32
#define HKV  8
#define HD   128
#define MAXS 2048

#define TSPLIT 4
#define CH   (MAXS / TSPLIT)   // 512

__device__ inline void fma4(float& a, float4 w, float4 x)
{
    a = fmaf(w.x, x.x, a);
    a = fmaf(w.y, x.y, a);
    a = fmaf(w.z, x.z, a);
    a = fmaf(w.w, x.w, a);
}

// ---------------------------------------------------------------------------
// GEMV-32, LDS-free: C[b, r] += sum_k W[r,k] * X[b,k] for 32 batch rows.
// Grid: (M/64, KSPLIT). Thread owns rows {2mg, 2mg+1} x b in {bg+8j}.
// W streams global->reg (8 lanes/mg broadcast-coalesce); X is L2-resident
// (512 KB) and read directly. No LDS, no barriers: pure FMA+load pipeline.
// Partials combined via fp32 atomicAdd (targets pre-zeroed).
// ---------------------------------------------------------------------------
__global__ __launch_bounds__(256)
void gemv32(const float* __restrict__ W, const float* __restrict__ X,
            float* __restrict__ C, int K, long strideB)
{
    const int tid = threadIdx.x;
    const int bg  = tid & 7;          // 8 b-groups, b = bg + 8j
    const int mg  = tid >> 3;         // 0..31 -> rows 2mg, 2mg+1
    const int row0 = blockIdx.x * 64;
    const int ks   = K / gridDim.y;
    const int kbeg = blockIdx.y * ks;

    const float* wp0 = W + (long)(row0 + 2 * mg) * K + kbeg;
    const float* wp1 = wp0 + K;
    const float* xp0 = X + (long)(bg +  0) * K + kbeg;
    const float* xp1 = X + (long)(bg +  8) * K + kbeg;
    const float* xp2 = X + (long)(bg + 16) * K + kbeg;
    const float* xp3 = X + (long)(bg + 24) * K + kbeg;

    float acc[2][4] = {};

    #pragma unroll 4
    for (int k = 0; k < ks; k += 4) {
        float4 w0 = *(const float4*)(wp0 + k);
        float4 w1 = *(const float4*)(wp1 + k);
        float4 x0 = *(const float4*)(xp0 + k);
        float4 x1 = *(const float4*)(xp1 + k);
        float4 x2 = *(const float4*)(xp2 + k);
        float4 x3 = *(const float4*)(xp3 + k);
        fma4(acc[0][0], w0, x0);  fma4(acc[1][0], w1, x0);
        fma4(acc[0][1], w0, x1);  fma4(acc[1][1], w1, x1);
        fma4(acc[0][2], w0, x2);  fma4(acc[1][2], w1, x2);
        fma4(acc[0][3], w0, x3);  fma4(acc[1][3], w1, x3);
    }

    #pragma unroll
    for (int j = 0; j < 4; ++j) {
        int b = bg + 8 * j;
        atomicAdd(&C[(long)b * strideB + row0 + mg * 2 + 0], acc[0][j]);
        atomicAdd(&C[(long)b * strideB + row0 + mg * 2 + 1], acc[1][j]);
    }
}

// ---------------------------------------------------------------------------
// RoPE on q (in-place) and k (k_new -> k_cache[b][start]), copy v into cache.
// ---------------------------------------------------------------------------
__global__ __launch_bounds__(256)
void rope_scatter(float* __restrict__ q_buf, const float* __restrict__ k_new,
                  const float* __restrict__ v_new, float* __restrict__ k_cache,
                  float* __restrict__ v_cache, const float* __restrict__ fc,
                  const float* __restrict__ fs, const int* __restrict__ sp)
{
    const int start = sp[0];
    const int gt = blockIdx.x * 256 + threadIdx.x;
    const int NT = gridDim.x * 256;

    for (int i = gt; i < NB * HQ * 64; i += NT) {
        int b = i >> 11, r = i & 2047, p = r & 63;
        float c = fc[p], s = fs[p];
        float2 xv = *(float2*)(q_buf + (long)b * DIM + 2 * r);
        float2 ov = make_float2(xv.x * c - xv.y * s, xv.x * s + xv.y * c);
        *(float2*)(q_buf + (long)b * DIM + 2 * r) = ov;
    }
    for (int i = gt; i < NB * HKV * 64; i += NT) {
        int b = i >> 9, r = i & 511, p = r & 63;
        float c = fc[p], s = fs[p];
        float2 xv = *(const float2*)(k_new + (long)b * (HKV * HD) + 2 * r);
        float2 ov = make_float2(xv.x * c - xv.y * s, xv.x * s + xv.y * c);
        *(float2*)(k_cache + ((long)b * MAXS + start) * (HKV * HD) + 2 * r) = ov;
    }
    for (int i = gt; i < NB * HKV * HD / 4; i += NT) {
        int b = i >> 8, j = i & 255;
        float4 v = *(const float4*)(v_new + (long)b * (HKV * HD) + 4 * j);
        *(float4*)(v_cache + ((long)b * MAXS + start) * (HKV * HD) + 4 * j) = v;
    }
}

// ---------------------------------------------------------------------------
// Flash-decoding attention, partial pass. Block = (kv-group g, batch b, chunk
// ts); 512 threads. K is staged through LDS in 32-row tiles with LINE-PERFECT
// loads (32 lanes x float4 = one full 512B K-row per instruction) -- fixes the
// 1.55x HBM over-fetch of the strided direct-read version. Q lives in regs.
// ---------------------------------------------------------------------------
__global__ __launch_bounds__(512)
void attention_part(const float* __restrict__ q_buf,
                    const float* __restrict__ k_cache,
                    const float* __restrict__ v_cache,
                    float* __restrict__ part_o,    // [NB][HKV][TSPLIT][4][HD]
                    float2* __restrict__ part_ml,  // [NB][HKV][TSPLIT][4]
                    const int* __restrict__ sp)
{
    const int g = blockIdx.x, b = blockIdx.y, ts = blockIdx.z;
    const int tid = threadIdx.x;
    const int wave = tid >> 6, lane = tid & 63;
    const int L = sp[0] + 1;          // 2048
    const int tbeg = ts * CH;

    __shared__ __align__(16) float kt[32][132];    // 16.9 KB, +4 pad
    __shared__ __align__(16) float sc_s[4][CH];    // 8 KB
    __shared__ float wred[8];
    __shared__ float m_sh[4], l_sh[4];
    float* outred = &kt[0][0];                     // alias (pass-2 phase only)

    const float scale = 0.08838834764831845f;  // 1/sqrt(128)
    const float* Kbase = k_cache + ((long)b * MAXS * HKV + g) * HD;

    // ---- Q into registers: thread covers (head hh, quarter e) -----------
    const int r  = tid >> 4;          // 0..31  row within K tile
    const int hh = (tid >> 2) & 3;    // head
    const int e  = tid & 3;           // quarter of HD (32 floats)
    float4 qreg[8];
    {
        const float* qsrc = q_buf + (long)b * DIM + g * 4 * HD + hh * HD + e * 32;
        #pragma unroll
        for (int c = 0; c < 8; ++c) qreg[c] = *(const float4*)(qsrc + c * 4);
    }

    // ---- pass 1: scores via LDS-staged K tiles (16 tiles x 32 rows) -----
    for (int tile = 0; tile < 16; ++tile) {
        const int base_t = tbeg + tile * 32;
        // stage: lane i covers (row i>>5, float4 col i&31): full rows,
        // every 128B line fetched by exactly one instruction, fully used.
        for (int i = tid; i < 32 * 32; i += 512) {
            int row = i >> 5, c4 = i & 31;
            *(float4*)&kt[row][c4 * 4] =
                *(const float4*)(Kbase + (long)(base_t + row) * (HKV * HD) + c4 * 4);
        }
        __syncthreads();
        float a = 0.f;
        #pragma unroll
        for (int c = 0; c < 8; ++c) {
            float4 kv = *(const float4*)&kt[r][e * 32 + c * 4];
            fma4(a, kv, qreg[c]);
        }
        a += __shfl_xor(a, 1, 64);
        a += __shfl_xor(a, 2, 64);
        if (e == 0) {
            int t = base_t + r;
            sc_s[hh][tile * 32 + r] = (t < L) ? a * scale : -3.0e38f;
        }
        __syncthreads();
    }

    // ---- chunk softmax (unnormalized): m, p=exp(s-m), l=sum p ----------
    const int h = tid >> 7, idx = tid & 127;
    {
        float mx = -3.0e38f;
        for (int tl = idx; tl < CH; tl += 128) mx = fmaxf(mx, sc_s[h][tl]);
        #pragma unroll
        for (int o = 32; o > 0; o >>= 1) mx = fmaxf(mx, __shfl_xor(mx, o, 64));
        if (lane == 0) wred[wave] = mx;
        __syncthreads();
        if (tid < 4) m_sh[tid] = fmaxf(wred[2 * tid], wred[2 * tid + 1]);
        __syncthreads();
        float m = m_sh[h];
        float ssum = 0.f;
        for (int tl = idx; tl < CH; tl += 128) {
            float sv = sc_s[h][tl];
            float p = (sv > -1.0e37f) ? __expf(sv - m) : 0.f;
            sc_s[h][tl] = p;
            ssum += p;
        }
        #pragma unroll
        for (int o = 32; o > 0; o >>= 1) ssum += __shfl_xor(ssum, o, 64);
        if (lane == 0) wred[wave] = ssum;
        __syncthreads();
        if (tid < 4) l_sh[tid] = wred[2 * tid] + wred[2 * tid + 1];
        __syncthreads();
    }

    // ---- pass 2: P . V, float4 V loads (line-perfect, contiguous) ------
    {
        const int hp = tid >> 7;            // head
        const int tc = (tid >> 5) & 3;      // t sub-chunk (CH/4 = 128 each)
        const int dq = tid & 31;            // float4 column
        const float* Vb = v_cache + ((long)b * MAXS * HKV + g) * HD + dq * 4;
        float4 a = make_float4(0.f, 0.f, 0.f, 0.f);
        const int tl0 = tc * (CH / 4);
        #pragma unroll 8
        for (int i = 0; i < CH / 4; ++i) {
            int tl = tl0 + i;
            float p = sc_s[hp][tl];         // broadcast within half-wave
            float4 v = *(const float4*)(Vb + (long)(tbeg + tl) * (HKV * HD));
            a.x = fmaf(p, v.x, a.x);
            a.y = fmaf(p, v.y, a.y);
            a.z = fmaf(p, v.z, a.z);
            a.w = fmaf(p, v.w, a.w);
        }
        *(float4*)&outred[(hp * 4 + tc) * HD + dq * 4] = a;
    }
    __syncthreads();
    {
        const int d = tid & 127;
        float o = outred[(h * 4 + 0) * HD + d] + outred[(h * 4 + 1) * HD + d]
                + outred[(h * 4 + 2) * HD + d] + outred[(h * 4 + 3) * HD + d];
        long po = ((((long)b * HKV + g) * TSPLIT + ts) * 4 + h) * HD + d;
        part_o[po] = o;
        if (d == 0)
            part_ml[(((long)b * HKV + g) * TSPLIT + ts) * 4 + h] =
                make_float2(m_sh[h], l_sh[h]);
    }
}

// ---------------------------------------------------------------------------
// Combine TSPLIT partials:  out = sum_ts e^{m_ts-M} O_ts / sum_ts e^{m_ts-M} l_ts
// ---------------------------------------------------------------------------
__global__ __launch_bounds__(512)
void attention_combine(const float* __restrict__ part_o,
                       const float2* __restrict__ part_ml,
                       float* __restrict__ attn)
{
    const int g = blockIdx.x, b = blockIdx.y;
    const int h = threadIdx.x >> 7, d = threadIdx.x & 127;
    const float2* ml = part_ml + ((long)b * HKV + g) * TSPLIT * 4 + h;
    float M = -3.0e38f;
    #pragma unroll
    for (int ts = 0; ts < TSPLIT; ++ts) M = fmaxf(M, ml[ts * 4].x);
    const float* po = part_o + (((long)b * HKV + g) * TSPLIT * 4 + h) * HD + d;
    float num = 0.f, denom = 0.f;
    #pragma unroll
    for (int ts = 0; ts < TSPLIT; ++ts) {
        float2 mlv = ml[ts * 4];
        float w = (mlv.x > -1.0e37f) ? __expf(mlv.x - M) : 0.f;
        denom += mlv.y * w;
        num   += po[(long)ts * 4 * HD] * w;
    }
    attn[(long)b * DIM + g * 4 * HD + h * HD + d] = num / denom;
}

// ---------------------------------------------------------------------------
extern "C" void kernel_launch(void* const* d_in, const int* in_sizes, int n_in,
                              void* d_out, int out_size, void* d_ws, size_t ws_size,
                              hipStream_t stream)
{
    const float* x    = (const float*)d_in[0];
    const float* fcos = (const float*)d_in[1];
    const float* fsin = (const float*)d_in[2];
    const float* wq   = (const float*)d_in[3];
    const float* wk   = (const float*)d_in[4];
    const float* wv   = (const float*)d_in[5];
    const float* wo   = (const float*)d_in[6];
    float* k_cache    = (float*)d_in[7];
    float* v_cache    = (float*)d_in[8];
    const int* sp     = (const int*)d_in[9];
    float* out        = (float*)d_out;

    float* q_buf = (float*)d_ws;                 // 131072 floats
    float* k_new = q_buf + NB * DIM;             // 32768
    float* v_new = k_new + NB * HKV * HD;        // 32768
    float* attn  = v_new + NB * HKV * HD;        // 131072
    float* part_o = attn + NB * DIM;             // 524288
    float2* part_ml = (float2*)(part_o + (long)NB * HKV * TSPLIT * 4 * HD);

    hipMemsetAsync(d_ws, 0, (size_t)(NB * DIM + 2 * NB * HKV * HD) * 4, stream);
    hipMemsetAsync(d_out, 0, (size_t)NB * DIM * 4, stream);

    gemv32<<<dim3(64, 8), 256, 0, stream>>>(wq, x, q_buf, DIM, DIM);
    gemv32<<<dim3(16, 16), 256, 0, stream>>>(wk, x, k_new, DIM, HKV * HD);
    gemv32<<<dim3(16, 16), 256, 0, stream>>>(wv, x, v_new, DIM, HKV * HD);
    rope_scatter<<<256, 256, 0, stream>>>(q_buf, k_new, v_new, k_cache, v_cache,
                                          fcos, fsin, sp);
    attention_part<<<dim3(HKV, NB, TSPLIT), 512, 0, stream>>>(
        q_buf, k_cache, v_cache, part_o, part_ml, sp);
    attention_combine<<<dim3(HKV, NB), 512, 0, stream>>>(part_o, part_ml, attn);
    gemv32<<<dim3(64, 8), 256, 0, stream>>>(wo, attn, out, DIM, DIM);
}

// Round 3
// 740.815 us; speedup vs baseline: 1.2701x; 1.2701x over previous
//
#include <hip/hip_runtime.h>

#define NB   32      // batch
#define DIM  4096
#define HQ   32
#define HKV  8
#define HD   128
#define MAXS 2048

#define TSPLIT 4
#define CH   (MAXS / TSPLIT)   // 512

__device__ inline void fma4(float& a, float4 w, float4 x)
{
    a = fmaf(w.x, x.x, a);
    a = fmaf(w.y, x.y, a);
    a = fmaf(w.z, x.z, a);
    a = fmaf(w.w, x.w, a);
}

// ---------------------------------------------------------------------------
// GEMV-32 (staged LDS, T14 async-stage): C[b,r] += sum_k W[r,k] * X[b,k].
// Grid: (M/64, KSPLIT). Block: 64 rows x 32 b, K-slice of K/KSPLIT.
// Staging is LINE-PERFECT (16 lanes cover 256B per W row); the next tile's
// global loads are issued into registers right after the barrier and written
// to LDS after compute, hiding HBM latency under the FMA loop (T14).
// Partials combined via fp32 atomicAdd (targets pre-zeroed).
// ---------------------------------------------------------------------------
__global__ __launch_bounds__(256)
void gemv32(const float* __restrict__ W, const float* __restrict__ X,
            float* __restrict__ C, int K, long strideB)
{
    __shared__ __align__(16) float xs[32][68];   // +4 pad: conflict-free
    __shared__ __align__(16) float wt[64][68];
    const int tid = threadIdx.x;
    const int bg  = tid & 7;          // 8 b-groups, b = bg + 8j
    const int mg  = tid >> 3;         // 0..31 -> rows 2mg, 2mg+1
    const int row0 = blockIdx.x * 64;
    const int ks   = K / gridDim.y;
    const int kbeg = blockIdx.y * ks;
    const int ntile = ks >> 6;        // 64-wide K tiles

    float4 xr[2], wr[4];
    // prefetch tile 0 into regs
    #pragma unroll
    for (int u = 0; u < 2; ++u) {
        int i = tid + 256 * u, b = i >> 4, kq = i & 15;
        xr[u] = *(const float4*)(X + (long)b * K + kbeg + kq * 4);
    }
    #pragma unroll
    for (int u = 0; u < 4; ++u) {
        int i = tid + 256 * u, m = i >> 4, kq = i & 15;
        wr[u] = *(const float4*)(W + (long)(row0 + m) * K + kbeg + kq * 4);
    }

    float acc[2][4] = {};

    for (int t = 0; t < ntile; ++t) {
        // write staged regs to LDS
        #pragma unroll
        for (int u = 0; u < 2; ++u) {
            int i = tid + 256 * u;
            *(float4*)&xs[i >> 4][(i & 15) * 4] = xr[u];
        }
        #pragma unroll
        for (int u = 0; u < 4; ++u) {
            int i = tid + 256 * u;
            *(float4*)&wt[i >> 4][(i & 15) * 4] = wr[u];
        }
        __syncthreads();

        // issue next tile's loads (latency hides under the FMA loop below)
        if (t + 1 < ntile) {
            const int k0 = kbeg + (t + 1) * 64;
            #pragma unroll
            for (int u = 0; u < 2; ++u) {
                int i = tid + 256 * u, b = i >> 4, kq = i & 15;
                xr[u] = *(const float4*)(X + (long)b * K + k0 + kq * 4);
            }
            #pragma unroll
            for (int u = 0; u < 4; ++u) {
                int i = tid + 256 * u, m = i >> 4, kq = i & 15;
                wr[u] = *(const float4*)(W + (long)(row0 + m) * K + k0 + kq * 4);
            }
        }

        #pragma unroll
        for (int kq = 0; kq < 16; ++kq) {
            float4 w0 = *(const float4*)&wt[mg * 2 + 0][kq * 4];
            float4 w1 = *(const float4*)&wt[mg * 2 + 1][kq * 4];
            #pragma unroll
            for (int j = 0; j < 4; ++j) {
                float4 xv = *(const float4*)&xs[bg + 8 * j][kq * 4];
                fma4(acc[0][j], w0, xv);
                fma4(acc[1][j], w1, xv);
            }
        }
        __syncthreads();
    }

    #pragma unroll
    for (int j = 0; j < 4; ++j) {
        int b = bg + 8 * j;
        atomicAdd(&C[(long)b * strideB + row0 + mg * 2 + 0], acc[0][j]);
        atomicAdd(&C[(long)b * strideB + row0 + mg * 2 + 1], acc[1][j]);
    }
}

// ---------------------------------------------------------------------------
// RoPE on q (in-place) and k (k_new -> k_cache[b][start]), copy v into cache.
// ---------------------------------------------------------------------------
__global__ __launch_bounds__(256)
void rope_scatter(float* __restrict__ q_buf, const float* __restrict__ k_new,
                  const float* __restrict__ v_new, float* __restrict__ k_cache,
                  float* __restrict__ v_cache, const float* __restrict__ fc,
                  const float* __restrict__ fs, const int* __restrict__ sp)
{
    const int start = sp[0];
    const int gt = blockIdx.x * 256 + threadIdx.x;
    const int NT = gridDim.x * 256;

    for (int i = gt; i < NB * HQ * 64; i += NT) {
        int b = i >> 11, r = i & 2047, p = r & 63;
        float c = fc[p], s = fs[p];
        float2 xv = *(float2*)(q_buf + (long)b * DIM + 2 * r);
        float2 ov = make_float2(xv.x * c - xv.y * s, xv.x * s + xv.y * c);
        *(float2*)(q_buf + (long)b * DIM + 2 * r) = ov;
    }
    for (int i = gt; i < NB * HKV * 64; i += NT) {
        int b = i >> 9, r = i & 511, p = r & 63;
        float c = fc[p], s = fs[p];
        float2 xv = *(const float2*)(k_new + (long)b * (HKV * HD) + 2 * r);
        float2 ov = make_float2(xv.x * c - xv.y * s, xv.x * s + xv.y * c);
        *(float2*)(k_cache + ((long)b * MAXS + start) * (HKV * HD) + 2 * r) = ov;
    }
    for (int i = gt; i < NB * HKV * HD / 4; i += NT) {
        int b = i >> 8, j = i & 255;
        float4 v = *(const float4*)(v_new + (long)b * (HKV * HD) + 4 * j);
        *(float4*)(v_cache + ((long)b * MAXS + start) * (HKV * HD) + 4 * j) = v;
    }
}

// ---------------------------------------------------------------------------
// Flash-decoding attention, partial pass. Block = (kv-group g, batch b, chunk
// ts); 512 threads. K staged through LDS in 32-row tiles with LINE-PERFECT
// loads; Q in registers; float4 V stream.
// ---------------------------------------------------------------------------
__global__ __launch_bounds__(512)
void attention_part(const float* __restrict__ q_buf,
                    const float* __restrict__ k_cache,
                    const float* __restrict__ v_cache,
                    float* __restrict__ part_o,    // [NB][HKV][TSPLIT][4][HD]
                    float2* __restrict__ part_ml,  // [NB][HKV][TSPLIT][4]
                    const int* __restrict__ sp)
{
    const int g = blockIdx.x, b = blockIdx.y, ts = blockIdx.z;
    const int tid = threadIdx.x;
    const int wave = tid >> 6, lane = tid & 63;
    const int L = sp[0] + 1;          // 2048
    const int tbeg = ts * CH;

    __shared__ __align__(16) float kt[32][132];    // 16.9 KB, +4 pad
    __shared__ __align__(16) float sc_s[4][CH];    // 8 KB
    __shared__ float wred[8];
    __shared__ float m_sh[4], l_sh[4];
    float* outred = &kt[0][0];                     // alias (pass-2 phase only)

    const float scale = 0.08838834764831845f;  // 1/sqrt(128)
    const float* Kbase = k_cache + ((long)b * MAXS * HKV + g) * HD;

    // ---- Q into registers: thread covers (head hh, quarter e) -----------
    const int r  = tid >> 4;          // 0..31  row within K tile
    const int hh = (tid >> 2) & 3;    // head
    const int e  = tid & 3;           // quarter of HD (32 floats)
    float4 qreg[8];
    {
        const float* qsrc = q_buf + (long)b * DIM + g * 4 * HD + hh * HD + e * 32;
        #pragma unroll
        for (int c = 0; c < 8; ++c) qreg[c] = *(const float4*)(qsrc + c * 4);
    }

    // ---- pass 1: scores via LDS-staged K tiles (16 tiles x 32 rows) -----
    for (int tile = 0; tile < 16; ++tile) {
        const int base_t = tbeg + tile * 32;
        for (int i = tid; i < 32 * 32; i += 512) {
            int row = i >> 5, c4 = i & 31;
            *(float4*)&kt[row][c4 * 4] =
                *(const float4*)(Kbase + (long)(base_t + row) * (HKV * HD) + c4 * 4);
        }
        __syncthreads();
        float a = 0.f;
        #pragma unroll
        for (int c = 0; c < 8; ++c) {
            float4 kv = *(const float4*)&kt[r][e * 32 + c * 4];
            fma4(a, kv, qreg[c]);
        }
        a += __shfl_xor(a, 1, 64);
        a += __shfl_xor(a, 2, 64);
        if (e == 0) {
            int t = base_t + r;
            sc_s[hh][tile * 32 + r] = (t < L) ? a * scale : -3.0e38f;
        }
        __syncthreads();
    }

    // ---- chunk softmax (unnormalized): m, p=exp(s-m), l=sum p ----------
    const int h = tid >> 7, idx = tid & 127;
    {
        float mx = -3.0e38f;
        for (int tl = idx; tl < CH; tl += 128) mx = fmaxf(mx, sc_s[h][tl]);
        #pragma unroll
        for (int o = 32; o > 0; o >>= 1) mx = fmaxf(mx, __shfl_xor(mx, o, 64));
        if (lane == 0) wred[wave] = mx;
        __syncthreads();
        if (tid < 4) m_sh[tid] = fmaxf(wred[2 * tid], wred[2 * tid + 1]);
        __syncthreads();
        float m = m_sh[h];
        float ssum = 0.f;
        for (int tl = idx; tl < CH; tl += 128) {
            float sv = sc_s[h][tl];
            float p = (sv > -1.0e37f) ? __expf(sv - m) : 0.f;
            sc_s[h][tl] = p;
            ssum += p;
        }
        #pragma unroll
        for (int o = 32; o > 0; o >>= 1) ssum += __shfl_xor(ssum, o, 64);
        if (lane == 0) wred[wave] = ssum;
        __syncthreads();
        if (tid < 4) l_sh[tid] = wred[2 * tid] + wred[2 * tid + 1];
        __syncthreads();
    }

    // ---- pass 2: P . V, float4 V loads (line-perfect, contiguous) ------
    {
        const int hp = tid >> 7;            // head
        const int tc = (tid >> 5) & 3;      // t sub-chunk (CH/4 = 128 each)
        const int dq = tid & 31;            // float4 column
        const float* Vb = v_cache + ((long)b * MAXS * HKV + g) * HD + dq * 4;
        float4 a = make_float4(0.f, 0.f, 0.f, 0.f);
        const int tl0 = tc * (CH / 4);
        #pragma unroll 8
        for (int i = 0; i < CH / 4; ++i) {
            int tl = tl0 + i;
            float p = sc_s[hp][tl];         // broadcast within half-wave
            float4 v = *(const float4*)(Vb + (long)(tbeg + tl) * (HKV * HD));
            a.x = fmaf(p, v.x, a.x);
            a.y = fmaf(p, v.y, a.y);
            a.z = fmaf(p, v.z, a.z);
            a.w = fmaf(p, v.w, a.w);
        }
        *(float4*)&outred[(hp * 4 + tc) * HD + dq * 4] = a;
    }
    __syncthreads();
    {
        const int d = tid & 127;
        float o = outred[(h * 4 + 0) * HD + d] + outred[(h * 4 + 1) * HD + d]
                + outred[(h * 4 + 2) * HD + d] + outred[(h * 4 + 3) * HD + d];
        long po = ((((long)b * HKV + g) * TSPLIT + ts) * 4 + h) * HD + d;
        part_o[po] = o;
        if (d == 0)
            part_ml[(((long)b * HKV + g) * TSPLIT + ts) * 4 + h] =
                make_float2(m_sh[h], l_sh[h]);
    }
}

// ---------------------------------------------------------------------------
// Combine TSPLIT partials:  out = sum_ts e^{m_ts-M} O_ts / sum_ts e^{m_ts-M} l_ts
// ---------------------------------------------------------------------------
__global__ __launch_bounds__(512)
void attention_combine(const float* __restrict__ part_o,
                       const float2* __restrict__ part_ml,
                       float* __restrict__ attn)
{
    const int g = blockIdx.x, b = blockIdx.y;
    const int h = threadIdx.x >> 7, d = threadIdx.x & 127;
    const float2* ml = part_ml + ((long)b * HKV + g) * TSPLIT * 4 + h;
    float M = -3.0e38f;
    #pragma unroll
    for (int ts = 0; ts < TSPLIT; ++ts) M = fmaxf(M, ml[ts * 4].x);
    const float* po = part_o + (((long)b * HKV + g) * TSPLIT * 4 + h) * HD + d;
    float num = 0.f, denom = 0.f;
    #pragma unroll
    for (int ts = 0; ts < TSPLIT; ++ts) {
        float2 mlv = ml[ts * 4];
        float w = (mlv.x > -1.0e37f) ? __expf(mlv.x - M) : 0.f;
        denom += mlv.y * w;
        num   += po[(long)ts * 4 * HD] * w;
    }
    attn[(long)b * DIM + g * 4 * HD + h * HD + d] = num / denom;
}

// ---------------------------------------------------------------------------
extern "C" void kernel_launch(void* const* d_in, const int* in_sizes, int n_in,
                              void* d_out, int out_size, void* d_ws, size_t ws_size,
                              hipStream_t stream)
{
    const float* x    = (const float*)d_in[0];
    const float* fcos = (const float*)d_in[1];
    const float* fsin = (const float*)d_in[2];
    const float* wq   = (const float*)d_in[3];
    const float* wk   = (const float*)d_in[4];
    const float* wv   = (const float*)d_in[5];
    const float* wo   = (const float*)d_in[6];
    float* k_cache    = (float*)d_in[7];
    float* v_cache    = (float*)d_in[8];
    const int* sp     = (const int*)d_in[9];
    float* out        = (float*)d_out;

    float* q_buf = (float*)d_ws;                 // 131072 floats
    float* k_new = q_buf + NB * DIM;             // 32768
    float* v_new = k_new + NB * HKV * HD;        // 32768
    float* attn  = v_new + NB * HKV * HD;        // 131072
    float* part_o = attn + NB * DIM;             // 524288
    float2* part_ml = (float2*)(part_o + (long)NB * HKV * TSPLIT * 4 * HD);

    hipMemsetAsync(d_ws, 0, (size_t)(NB * DIM + 2 * NB * HKV * HD) * 4, stream);
    hipMemsetAsync(d_out, 0, (size_t)NB * DIM * 4, stream);

    gemv32<<<dim3(64, 8), 256, 0, stream>>>(wq, x, q_buf, DIM, DIM);
    gemv32<<<dim3(16, 16), 256, 0, stream>>>(wk, x, k_new, DIM, HKV * HD);
    gemv32<<<dim3(16, 16), 256, 0, stream>>>(wv, x, v_new, DIM, HKV * HD);
    rope_scatter<<<256, 256, 0, stream>>>(q_buf, k_new, v_new, k_cache, v_cache,
                                          fcos, fsin, sp);
    attention_part<<<dim3(HKV, NB, TSPLIT), 512, 0, stream>>>(
        q_buf, k_cache, v_cache, part_o, part_ml, sp);
    attention_combine<<<dim3(HKV, NB), 512, 0, stream>>>(part_o, part_ml, attn);
    gemv32<<<dim3(64, 8), 256, 0, stream>>>(wo, attn, out, DIM, DIM);
}